// Round 1
// baseline (49.719 us; speedup 1.0000x reference)
//
#include <hip/hip_runtime.h>
#include <math.h>

constexpr int CIN = 32;   // input channels
constexpr int NS  = 32;   // sums (output channels)

// Kernel 1: w[c][s] = softmax over c of accumulators[c][s]  (exp(log_softmax))
// accumulators layout: [1,1,CIN,NS] -> flat c*NS + s
__global__ void compute_w_kernel(const float* __restrict__ acc,
                                 float* __restrict__ w) {
    int s = threadIdx.x;
    if (s >= NS) return;
    float a[CIN];
    float m = -INFINITY;
#pragma unroll
    for (int c = 0; c < CIN; ++c) {
        a[c] = acc[c * NS + s];
        m = fmaxf(m, a[c]);
    }
    float sum = 0.0f;
#pragma unroll
    for (int c = 0; c < CIN; ++c) {
        a[c] = __expf(a[c] - m);
        sum += a[c];
    }
    float inv = 1.0f / sum;
#pragma unroll
    for (int c = 0; c < CIN; ++c) {
        w[c * NS + s] = a[c] * inv;
    }
}

// Kernel 2: one thread per pixel.
// out[pix][s] = m + log( sum_c exp(x[pix][c] - m) * w[c][s] )
// w is indexed with wave-uniform indices -> scalar loads via K$.
__global__ __launch_bounds__(256)
void logconv_kernel(const float* __restrict__ x,
                    const float* __restrict__ w,
                    float* __restrict__ out,
                    int npix) {
    int pix = blockIdx.x * blockDim.x + threadIdx.x;
    if (pix >= npix) return;

    const float4* xv = reinterpret_cast<const float4*>(x + (size_t)pix * CIN);

    float xr[CIN];
#pragma unroll
    for (int i = 0; i < CIN / 4; ++i) {
        float4 v = xv[i];
        xr[4 * i + 0] = v.x;
        xr[4 * i + 1] = v.y;
        xr[4 * i + 2] = v.z;
        xr[4 * i + 3] = v.w;
    }

    float m = xr[0];
#pragma unroll
    for (int c = 1; c < CIN; ++c) m = fmaxf(m, xr[c]);

    // p = exp(x - m), overwrite xr to save registers
#pragma unroll
    for (int c = 0; c < CIN; ++c) xr[c] = __expf(xr[c] - m);

    float accu[NS];
#pragma unroll
    for (int s = 0; s < NS; ++s) accu[s] = 0.0f;

#pragma unroll
    for (int c = 0; c < CIN; ++c) {
        float pc = xr[c];
#pragma unroll
        for (int s = 0; s < NS; ++s) {
            accu[s] = fmaf(pc, w[c * NS + s], accu[s]);
        }
    }

    float4* ov = reinterpret_cast<float4*>(out + (size_t)pix * NS);
#pragma unroll
    for (int i = 0; i < NS / 4; ++i) {
        float4 v;
        v.x = m + __logf(accu[4 * i + 0]);
        v.y = m + __logf(accu[4 * i + 1]);
        v.z = m + __logf(accu[4 * i + 2]);
        v.w = m + __logf(accu[4 * i + 3]);
        ov[i] = v;
    }
}

extern "C" void kernel_launch(void* const* d_in, const int* in_sizes, int n_in,
                              void* d_out, int out_size, void* d_ws, size_t ws_size,
                              hipStream_t stream) {
    const float* x   = (const float*)d_in[0];   // [32,128,128,32] f32
    const float* acc = (const float*)d_in[1];   // [1,1,32,32] f32
    float* out = (float*)d_out;                 // [32,128,128,32] f32
    float* w   = (float*)d_ws;                  // 32*32 f32 scratch

    // Stage 1: tiny softmax of accumulators -> w in workspace
    compute_w_kernel<<<1, 64, 0, stream>>>(acc, w);

    // Stage 2: main fused kernel, one thread per pixel
    int npix = in_sizes[0] / CIN;               // 524288
    int block = 256;
    int grid = (npix + block - 1) / block;      // 2048
    logconv_kernel<<<grid, block, 0, stream>>>(x, w, out, npix);
}

// Round 2
// 33.157 us; speedup vs baseline: 1.4995x; 1.4995x over previous
//
#include <hip/hip_runtime.h>
#include <math.h>

constexpr int CIN = 32;   // input channels (K)
constexpr int NS  = 32;   // sums (output channels)

typedef __attribute__((ext_vector_type(8)))  short  short8;
typedef __attribute__((ext_vector_type(16))) float  f32x16;

__device__ __forceinline__ short f2bf(float f) {
    union { float f; unsigned u; } v; v.f = f;
    unsigned r = (v.u + 0x7FFFu + ((v.u >> 16) & 1u)) >> 16;   // RNE
    return (short)r;
}

// w^T in bf16: wT[s][c] = softmax_c(acc[c][s])
__global__ void compute_w_kernel(const float* __restrict__ acc,
                                 short* __restrict__ wT) {
    int s = threadIdx.x;
    if (s >= NS) return;
    float a[CIN];
    float m = -INFINITY;
#pragma unroll
    for (int c = 0; c < CIN; ++c) { a[c] = acc[c * NS + s]; m = fmaxf(m, a[c]); }
    float sum = 0.f;
#pragma unroll
    for (int c = 0; c < CIN; ++c) { a[c] = __expf(a[c] - m); sum += a[c]; }
    float inv = 1.f / sum;
#pragma unroll
    for (int c = 0; c < CIN; ++c) wT[s * CIN + c] = f2bf(a[c] * inv);
}

// One wave = 32 pixels. D = A(w: s x c) * B(p: c x pixel) via 2x mfma_32x32x16_bf16.
// A frag: lane holds row=lane&31 (=s), k=8*(lane>>5)+j  -> wT[s][8h+j] (+16 for frag1)
// B frag: lane holds col=lane&31 (=pixel), k=8*(lane>>5)+j -> p[pix][8h+j] (+16)
// D:      lane holds col=lane&31 (=pixel), rows s=(reg&3)+8*(reg>>2)+4*(lane>>5)
__global__ __launch_bounds__(256)
void logconv_mfma(const float* __restrict__ x,
                  const short* __restrict__ wT,
                  float* __restrict__ out) {
    const int lane = threadIdx.x & 63;
    const int wid  = threadIdx.x >> 6;
    const int r    = lane & 31;          // pixel-within-wave / s-row for A
    const int h    = lane >> 5;          // K-half
    const long pix = (long)blockIdx.x * 128 + wid * 32 + r;

    const float* xp = x + pix * CIN + 8 * h;
    float4 a0 = *(const float4*)(xp);        // c = 8h .. 8h+3
    float4 a1 = *(const float4*)(xp + 4);    // c = 8h+4 .. 8h+7
    float4 a2 = *(const float4*)(xp + 16);   // c = 16+8h ..
    float4 a3 = *(const float4*)(xp + 20);

    float xv[16] = {a0.x,a0.y,a0.z,a0.w, a1.x,a1.y,a1.z,a1.w,
                    a2.x,a2.y,a2.z,a2.w, a3.x,a3.y,a3.z,a3.w};

    float pm = xv[0];
#pragma unroll
    for (int j = 1; j < 16; ++j) pm = fmaxf(pm, xv[j]);
    pm = fmaxf(pm, __shfl_xor(pm, 32));      // other 16 channels of same pixel

    short8 p0, p1;
#pragma unroll
    for (int j = 0; j < 8; ++j) p0[j] = f2bf(__expf(xv[j]     - pm));
#pragma unroll
    for (int j = 0; j < 8; ++j) p1[j] = f2bf(__expf(xv[8 + j] - pm));

    const short* wp = wT + r * CIN + 8 * h;
    short8 w0 = *(const short8*)(wp);        // c = 8h..8h+7   (k = 8h+j)
    short8 w1 = *(const short8*)(wp + 16);   // c = 16+8h..    (k' = 8h+j)

    f32x16 acc;
#pragma unroll
    for (int i = 0; i < 16; ++i) acc[i] = 0.f;
    acc = __builtin_amdgcn_mfma_f32_32x32x16_bf16(w0, p0, acc, 0, 0, 0);
    acc = __builtin_amdgcn_mfma_f32_32x32x16_bf16(w1, p1, acc, 0, 0, 0);

    // lane owns pixel `pix`; acc[4g+i] is s = 8g + 4h + i  -> float4 stores
    float* op = out + pix * NS;
#pragma unroll
    for (int g = 0; g < 4; ++g) {
        float4 v;
        v.x = pm + __logf(acc[4 * g + 0]);
        v.y = pm + __logf(acc[4 * g + 1]);
        v.z = pm + __logf(acc[4 * g + 2]);
        v.w = pm + __logf(acc[4 * g + 3]);
        *(float4*)(op + 8 * g + 4 * h) = v;
    }
}

extern "C" void kernel_launch(void* const* d_in, const int* in_sizes, int n_in,
                              void* d_out, int out_size, void* d_ws, size_t ws_size,
                              hipStream_t stream) {
    const float* x   = (const float*)d_in[0];   // [32,128,128,32] f32
    const float* acc = (const float*)d_in[1];   // [1,1,32,32] f32
    float* out = (float*)d_out;
    short* wT  = (short*)d_ws;                  // 32*32 bf16 (transposed)

    compute_w_kernel<<<1, 64, 0, stream>>>(acc, wT);

    int npix  = in_sizes[0] / CIN;              // 524288
    int grid  = npix / 128;                     // 4096 blocks x 256 thr (4 waves)
    logconv_mfma<<<grid, 256, 0, stream>>>(x, wT, out);
}